// Round 2
// baseline (746.842 us; speedup 1.0000x reference)
//
#include <hip/hip_runtime.h>

#define OD 26
#define OH 122
#define OW 122
#define GS (128*128)
#define NOUT (OD*OH*OW)

// Guide LDS tile for a 16x8x4 voxel block (2 x-adjacent voxels per thread):
// needs 22 x 14 x 10 floats. TLX padded 22 -> 24. TLX=24 is REQUIRED for the
// bank layout: the LDS conflict domain is the 32-lane HALF-wave (ty 0..3 /
// 4..7), and {ty*24 mod 32} = {0,24,16,8} covers each bank-octet start
// exactly once, so every ds_read lands 1 lane/bank per phase (measured: TLX
// 14 and 20 both leave 2-way holes in the half-wave -> identical 1.6 cyc/read
// conflict tax). 24*14*10 = 3360 floats = 13.44 KB.
#define TLX 24
#define TLY 14
#define TLZ 10
#define TLSLICE (TLX*TLY)      // 336
#define TLN (TLSLICE*TLZ)      // 3360

// Stage 0: domain kernel dk[27] — voxel-independent, computed once.
__global__ void compute_dk_kernel(const float* __restrict__ dn,
                                  const float* __restrict__ dw0, const float* __restrict__ db0,
                                  const float* __restrict__ dw1, const float* __restrict__ db1,
                                  float* __restrict__ dk_out) {
    __shared__ float d0[125];
    int t = threadIdx.x;
    if (t < 125) {
        int tz = t / 25, ty = (t / 5) % 5, tx = t % 5;
        float acc = db0[0];
        #pragma unroll
        for (int kz = 0; kz < 3; ++kz)
            #pragma unroll
            for (int ky = 0; ky < 3; ++ky)
                #pragma unroll
                for (int kx = 0; kx < 3; ++kx)
                    acc += dw0[kz*9 + ky*3 + kx] *
                           dn[(1+tz+kz)*81 + (1+ty+ky)*9 + (1+tx+kx)];
        d0[t] = fmaxf(acc, 0.0f);
    }
    __syncthreads();
    if (t < 27) {
        int rz = t / 9, ry = (t / 3) % 3, rx = t % 3;
        float acc = db1[0];
        #pragma unroll
        for (int kz = 0; kz < 3; ++kz)
            #pragma unroll
            for (int ky = 0; ky < 3; ++ky)
                #pragma unroll
                for (int kx = 0; kx < 3; ++kx)
                    acc += dw1[kz*9 + ky*3 + kx] * d0[(rz+kz)*25 + (ry+ky)*5 + (rx+kx)];
        dk_out[t] = fmaxf(acc, 0.0f);
    }
}

// Block = 16x8x4 voxel tile, 256 threads, each thread owns TWO x-adjacent
// voxels (x0 = xb+2*tx and x0+1). Rationale (R6): rocprof showed the LDS read
// pipe ~80% saturated (735 scalar ds_read_b32/thread at ~7.4 cyc incl. the
// 1.6 cyc half-wave conflict tax). The pair shares every guide row: 8 words
// feed both 7-word windows, read as 4x ds_read_b64 (base word 2*tx + even
// strides -> 8B-aligned). LDS instructions/voxel: 735 -> 210, conflict-free.
//
// conv1 stays ONE z-slice at a time (t0sA/B[25]) drained into rk accumulators
// (R5's spill-free structure). The asm memory clobber between slices is
// REQUIRED: without it LLVM CSEs the re-read rows across slices and rebuilds
// a full-tile live range (AGPR/scratch blowup — R3's failure mode).
// Weights land in SGPRs (uniform s_load, verified R5: 96 SGPR / 76 VGPR).
// Watch WRITE_SIZE: jump from ~2.7e3 KB to GB-scale means scratch spill.
__global__ __launch_bounds__(256, 3) void jbf_main_kernel(
        const float* __restrict__ x, const float* __restrict__ guide,
        const float* __restrict__ rw0p, const float* __restrict__ rb0p,
        const float* __restrict__ rw1p, const float* __restrict__ rb1p,
        const float* __restrict__ dkp, float* __restrict__ out) {
    __shared__ float gl[TLN];

    const int xb = blockIdx.x * 16;
    const int yb = blockIdx.y * 8;
    const int zb = blockIdx.z * 4;

    // Cooperative guide staging, coords clamped (edge tiles read dup rows;
    // in-range voxels only consume in-bounds neighbors, so values are exact.
    // Pad columns gx>=22 are never read; clamped loads keep them in-bounds).
    for (int i = threadIdx.x; i < TLN; i += 256) {
        const int gx = i % TLX;
        const int gy = (i / TLX) % TLY;
        const int gz = i / TLSLICE;
        const int sx = min(xb + gx, 127);
        const int sy = min(yb + gy, 127);
        const int sz = min(zb + gz, 31);
        gl[i] = guide[sz*GS + sy*128 + sx];
    }
    __syncthreads();

    const int tx = threadIdx.x & 7;
    const int ty = (threadIdx.x >> 3) & 7;
    const int tz = threadIdx.x >> 6;
    const int x0 = xb + 2*tx;            // voxel A; voxel B = x0+1
    const int y0 = yb + ty;
    const int z0 = zb + tz;
    if (y0 >= OH || z0 >= OD) return;    // x handled per-voxel at the store

    // Wave-uniform weights -> SGPRs (uniform loads; survive the clobbers as
    // SSA values — only LDS reads are re-issued per slice).
    float rw0[27], rw1[27];
    #pragma unroll
    for (int i = 0; i < 27; ++i) { rw0[i] = rw0p[i]; rw1[i] = rw1p[i]; }
    const float rb0 = rb0p[0], rb1 = rb1p[0];

    // Per-thread LDS base: all inner reads are base + compile-time offset,
    // 8-byte aligned (even base word, even offsets).
    const float* glb = &gl[tz*TLSLICE + ty*TLX + 2*tx];
    const float gcA = glb[3*TLSLICE + 3*TLX + 3];
    const float gcB = glb[3*TLSLICE + 3*TLX + 4];

    // conv2 accumulators for both voxels (bias added once here).
    float rkA[27], rkB[27];
    #pragma unroll
    for (int i = 0; i < 27; ++i) { rkA[i] = rb1; rkB[i] = rb1; }

    #pragma unroll
    for (int tz1 = 0; tz1 < 5; ++tz1) {
        // conv1, z-slice tz1, both voxels in lockstep (identical guide rows).
        float tA[25], tB[25];
        #pragma unroll
        for (int i = 0; i < 25; ++i) { tA[i] = rb0; tB[i] = rb0; }

        #pragma unroll
        for (int kz = 0; kz < 3; ++kz) {
            const int gz = tz1 + kz;
            #pragma unroll
            for (int gy = 0; gy < 7; ++gy) {
                // One row: 8 words via 4x ds_read_b64, feeds both windows.
                float w[8];
                #pragma unroll
                for (int j = 0; j < 4; ++j) {
                    const float2 v = *reinterpret_cast<const float2*>(
                        glb + gz*TLSLICE + gy*TLX + 2*j);
                    w[2*j]   = v.x;
                    w[2*j+1] = v.y;
                }
                float sA[7], sB[7];
                #pragma unroll
                for (int j = 0; j < 7; ++j) {
                    sA[j] = w[j]   - gcA;
                    sB[j] = w[j+1] - gcB;
                }
                #pragma unroll
                for (int ky = 0; ky < 3; ++ky) {
                    const int ty1 = gy - ky;
                    if (ty1 < 0 || ty1 > 4) continue;          // folds at compile time
                    #pragma unroll
                    for (int txx = 0; txx < 5; ++txx)
                        #pragma unroll
                        for (int kx = 0; kx < 3; ++kx) {
                            const float rw = rw0[kz*9 + ky*3 + kx];
                            tA[ty1*5 + txx] = fmaf(rw, fabsf(sA[txx + kx]), tA[ty1*5 + txx]);
                            tB[ty1*5 + txx] = fmaf(rw, fabsf(sB[txx + kx]), tB[ty1*5 + txx]);
                        }
                }
            }
        }
        #pragma unroll
        for (int i = 0; i < 25; ++i) { tA[i] = fmaxf(tA[i], 0.0f); tB[i] = fmaxf(tB[i], 0.0f); }

        // Drain slice into conv2 accumulators: rk(rz,·,·) gets the kz2 = tz1-rz tap.
        #pragma unroll
        for (int kz2 = 0; kz2 < 3; ++kz2) {
            const int rz = tz1 - kz2;
            if (rz < 0 || rz > 2) continue;                    // folds at compile time
            #pragma unroll
            for (int ry = 0; ry < 3; ++ry)
                #pragma unroll
                for (int rx = 0; rx < 3; ++rx) {
                    #pragma unroll
                    for (int ky2 = 0; ky2 < 3; ++ky2)
                        #pragma unroll
                        for (int kx2 = 0; kx2 < 3; ++kx2) {
                            const float rw = rw1[kz2*9 + ky2*3 + kx2];
                            const float tv = 0.0f; (void)tv;
                            rkA[rz*9 + ry*3 + rx] =
                                fmaf(rw, tA[(ry+ky2)*5 + (rx+kx2)], rkA[rz*9 + ry*3 + rx]);
                            rkB[rz*9 + ry*3 + rx] =
                                fmaf(rw, tB[(ry+ky2)*5 + (rx+kx2)], rkB[rz*9 + ry*3 + rx]);
                        }
                }
        }

        // Block LDS-load CSE across slices — keeps per-slice pressure bounded.
        asm volatile("" ::: "memory");
    }

    // Epilogue: relu(rk) * dk weighting + normalized reduction, both voxels.
    float numA = 0.0f, denA = 0.0f, numB = 0.0f, denB = 0.0f;
    const float* xbp = x + (z0+2)*GS + (y0+2)*128 + (x0+2);
    #pragma unroll
    for (int rz = 0; rz < 3; ++rz)
        #pragma unroll
        for (int ry = 0; ry < 3; ++ry)
            #pragma unroll
            for (int rx = 0; rx < 3; ++rx) {
                const float dkv = dkp[rz*9 + ry*3 + rx];
                const float wA = dkv * fmaxf(rkA[rz*9 + ry*3 + rx], 0.0f) + 1e-10f;
                const float wB = dkv * fmaxf(rkB[rz*9 + ry*3 + rx], 0.0f) + 1e-10f;
                const float xv0 = xbp[rz*GS + ry*128 + rx];
                const float xv1 = xbp[rz*GS + ry*128 + rx + 1];
                denA += wA;
                numA = fmaf(wA, xv0, numA);
                denB += wB;
                numB = fmaf(wB, xv1, numB);
            }

    if (x0 < OW)     out[(z0*OH + y0)*OW + x0]     = numA / denA;
    if (x0 + 1 < OW) out[(z0*OH + y0)*OW + x0 + 1] = numB / denB;
}

extern "C" void kernel_launch(void* const* d_in, const int* in_sizes, int n_in,
                              void* d_out, int out_size, void* d_ws, size_t ws_size,
                              hipStream_t stream) {
    const float* x     = (const float*)d_in[0];
    const float* dn    = (const float*)d_in[1];
    const float* guide = (const float*)d_in[2];
    const float* rw0   = (const float*)d_in[3];
    const float* rb0   = (const float*)d_in[4];
    const float* rw1   = (const float*)d_in[5];
    const float* rb1   = (const float*)d_in[6];
    const float* dw0   = (const float*)d_in[7];
    const float* db0   = (const float*)d_in[8];
    const float* dw1   = (const float*)d_in[9];
    const float* db1   = (const float*)d_in[10];
    float* out = (float*)d_out;
    float* dk  = (float*)d_ws;   // 27 floats

    compute_dk_kernel<<<1, 128, 0, stream>>>(dn, dw0, db0, dw1, db1, dk);

    dim3 grid((OW + 15) / 16, (OH + 7) / 8, (OD + 3) / 4);   // 8 x 16 x 7
    jbf_main_kernel<<<grid, 256, 0, stream>>>(x, guide, rw0, rb0, rw1, rb1, dk, out);
}

// Round 3
// 146.390 us; speedup vs baseline: 5.1017x; 5.1017x over previous
//
#include <hip/hip_runtime.h>

#define OD 26
#define OH 122
#define OW 122
#define GS (128*128)
#define NOUT (OD*OH*OW)

// Guide LDS tile for an 8x8x4 voxel block: needs 14 x 14 x 10 floats.
// TLX padded 14 -> 24. The LDS conflict domain is the 32-lane HALF-wave
// (ty 0..3 within a wave); bank start per ty row is (ty*TLX) mod 32.
// TLX=24 gives {0,24,16,8} -> every scalar ds_read_b32 covers all 32 banks
// exactly once (conflict-free). TLX=14 gave {0,14,28,10} and TLX=20 gave
// {0,20,8,28} -> both leave 2-lane pileups (measured identical 1.6 cyc/read
// conflict tax, SQ_LDS_BANK_CONFLICT ~8.6M). 24*14*10 = 3360 fl = 13.44 KB.
#define TLX 24
#define TLY 14
#define TLZ 10
#define TLSLICE (TLX*TLY)      // 336
#define TLN (TLSLICE*TLZ)      // 3360

// Stage 0: domain kernel dk[27] — voxel-independent, computed once.
__global__ void compute_dk_kernel(const float* __restrict__ dn,
                                  const float* __restrict__ dw0, const float* __restrict__ db0,
                                  const float* __restrict__ dw1, const float* __restrict__ db1,
                                  float* __restrict__ dk_out) {
    __shared__ float d0[125];
    int t = threadIdx.x;
    if (t < 125) {
        int tz = t / 25, ty = (t / 5) % 5, tx = t % 5;
        float acc = db0[0];
        #pragma unroll
        for (int kz = 0; kz < 3; ++kz)
            #pragma unroll
            for (int ky = 0; ky < 3; ++ky)
                #pragma unroll
                for (int kx = 0; kx < 3; ++kx)
                    acc += dw0[kz*9 + ky*3 + kx] *
                           dn[(1+tz+kz)*81 + (1+ty+ky)*9 + (1+tx+kx)];
        d0[t] = fmaxf(acc, 0.0f);
    }
    __syncthreads();
    if (t < 27) {
        int rz = t / 9, ry = (t / 3) % 3, rx = t % 3;
        float acc = db1[0];
        #pragma unroll
        for (int kz = 0; kz < 3; ++kz)
            #pragma unroll
            for (int ky = 0; ky < 3; ++ky)
                #pragma unroll
                for (int kx = 0; kx < 3; ++kx)
                    acc += dw1[kz*9 + ky*3 + kx] * d0[(rz+kz)*25 + (ry+ky)*5 + (rx+kx)];
        dk_out[t] = fmaxf(acc, 0.0f);
    }
}

// Block = 8x8x4 voxel tile (256 threads), ONE voxel per thread — the R5
// structure, which is the only shape this allocator has handled spill-free.
// HISTORY (do not repeat):
//   R2/R3: (64,4) hint / rolling window  -> ~800B/thread scratch, 3x slower.
//   R6:    two voxels/thread (live ~136 vals under a 168 cap) -> 4.8KB/thread
//          scratch, WRITE_SIZE 926MB, 9x slower. Per-thread state must stay
//          at R5 level (~85 values) unless the formulation packs registers.
// R7 changes vs R5 (all low-risk, counters-driven):
//   1. abs hoisted: a[j] = fabsf(w-gc) ONCE per element. R5's VALUBusy
//      implied ~10k instr/thread vs ~5.4k counted -> fabsf inside each FMA
//      was almost certainly emitted as a separate v_and per tap (3375 extra).
//   2. TLX=24 (see above) -> conflict-free LDS reads.
//   3. launch_bounds (256,4): cap 128 VGPR >> ~84 demand, 16 waves/CU.
// The asm memory clobber between slices is REQUIRED (blocks cross-slice LDS
// CSE that would rebuild the full-tile live range — R3's failure mode).
__global__ __launch_bounds__(256, 4) void jbf_main_kernel(
        const float* __restrict__ x, const float* __restrict__ guide,
        const float* __restrict__ rw0p, const float* __restrict__ rb0p,
        const float* __restrict__ rw1p, const float* __restrict__ rb1p,
        const float* __restrict__ dkp, float* __restrict__ out) {
    __shared__ float gl[TLN];

    const int xb = blockIdx.x * 8;
    const int yb = blockIdx.y * 8;
    const int zb = blockIdx.z * 4;

    // Cooperative guide staging, coords clamped (edge tiles read dup rows;
    // in-range voxels only consume in-bounds neighbors, so values are exact.
    // Pad columns gx>=14 are never read; clamped loads keep them in-bounds).
    for (int i = threadIdx.x; i < TLN; i += 256) {
        const int gx = i % TLX;
        const int gy = (i / TLX) % TLY;
        const int gz = i / TLSLICE;
        const int sx = min(xb + gx, 127);
        const int sy = min(yb + gy, 127);
        const int sz = min(zb + gz, 31);
        gl[i] = guide[sz*GS + sy*128 + sx];
    }
    __syncthreads();

    const int tx = threadIdx.x & 7;
    const int ty = (threadIdx.x >> 3) & 7;
    const int tz = threadIdx.x >> 6;
    const int x0 = xb + tx;
    const int y0 = yb + ty;
    const int z0 = zb + tz;
    if (x0 >= OW || y0 >= OH || z0 >= OD) return;

    // Wave-uniform weights -> SGPRs (uniform loads; survive the clobbers as
    // SSA values — only LDS reads are re-issued per slice).
    float rw0[27], rw1[27];
    #pragma unroll
    for (int i = 0; i < 27; ++i) { rw0[i] = rw0p[i]; rw1[i] = rw1p[i]; }
    const float rb0 = rb0p[0], rb1 = rb1p[0];

    // Per-thread LDS base: all inner reads are base + compile-time offset.
    const float* glb = &gl[tz*TLSLICE + ty*TLX + tx];
    const float gc = glb[3*TLSLICE + 3*TLX + 3];

    // conv2 accumulators (bias added once here; slice contributions add in).
    float rk[27];
    #pragma unroll
    for (int i = 0; i < 27; ++i) rk[i] = rb1;

    #pragma unroll
    for (int tz1 = 0; tz1 < 5; ++tz1) {
        // conv1, z-slice tz1: t0s(ty1,txx) = relu(rb0 + sum_k rw0(k)*a)
        float t0s[25];
        #pragma unroll
        for (int i = 0; i < 25; ++i) t0s[i] = rb0;

        #pragma unroll
        for (int kz = 0; kz < 3; ++kz) {
            const int gz = tz1 + kz;
            #pragma unroll
            for (int gy = 0; gy < 7; ++gy) {
                // Row abs-diffs computed ONCE (sub+and per element), FMAs
                // consume clean positives — no per-tap v_and.
                float a[7];
                #pragma unroll
                for (int j = 0; j < 7; ++j)
                    a[j] = fabsf(glb[gz*TLSLICE + gy*TLX + j] - gc);
                #pragma unroll
                for (int ky = 0; ky < 3; ++ky) {
                    const int ty1 = gy - ky;
                    if (ty1 < 0 || ty1 > 4) continue;          // folds at compile time
                    #pragma unroll
                    for (int txx = 0; txx < 5; ++txx)
                        #pragma unroll
                        for (int kx = 0; kx < 3; ++kx)
                            t0s[ty1*5 + txx] =
                                fmaf(rw0[kz*9 + ky*3 + kx], a[txx + kx],
                                     t0s[ty1*5 + txx]);
                }
            }
        }
        #pragma unroll
        for (int i = 0; i < 25; ++i) t0s[i] = fmaxf(t0s[i], 0.0f);

        // Drain slice into conv2 accumulators: rk(rz,·,·) gets the kz2 = tz1-rz tap.
        #pragma unroll
        for (int kz2 = 0; kz2 < 3; ++kz2) {
            const int rz = tz1 - kz2;
            if (rz < 0 || rz > 2) continue;                    // folds at compile time
            #pragma unroll
            for (int ry = 0; ry < 3; ++ry)
                #pragma unroll
                for (int rx = 0; rx < 3; ++rx) {
                    #pragma unroll
                    for (int ky2 = 0; ky2 < 3; ++ky2)
                        #pragma unroll
                        for (int kx2 = 0; kx2 < 3; ++kx2)
                            rk[rz*9 + ry*3 + rx] =
                                fmaf(rw1[kz2*9 + ky2*3 + kx2],
                                     t0s[(ry+ky2)*5 + (rx+kx2)],
                                     rk[rz*9 + ry*3 + rx]);
                }
        }

        // Block LDS-load CSE across slices — keeps per-slice pressure bounded.
        asm volatile("" ::: "memory");
    }

    // Epilogue: relu(rk) * dk weighting + normalized reduction.
    float num = 0.0f, den = 0.0f;
    const float* xbp = x + (z0+2)*GS + (y0+2)*128 + (x0+2);
    #pragma unroll
    for (int rz = 0; rz < 3; ++rz)
        #pragma unroll
        for (int ry = 0; ry < 3; ++ry)
            #pragma unroll
            for (int rx = 0; rx < 3; ++rx) {
                const float w = dkp[rz*9 + ry*3 + rx]
                              * fmaxf(rk[rz*9 + ry*3 + rx], 0.0f) + 1e-10f;
                den += w;
                num = fmaf(w, xbp[rz*GS + ry*128 + rx], num);
            }

    out[(z0*OH + y0)*OW + x0] = num / den;
}

extern "C" void kernel_launch(void* const* d_in, const int* in_sizes, int n_in,
                              void* d_out, int out_size, void* d_ws, size_t ws_size,
                              hipStream_t stream) {
    const float* x     = (const float*)d_in[0];
    const float* dn    = (const float*)d_in[1];
    const float* guide = (const float*)d_in[2];
    const float* rw0   = (const float*)d_in[3];
    const float* rb0   = (const float*)d_in[4];
    const float* rw1   = (const float*)d_in[5];
    const float* rb1   = (const float*)d_in[6];
    const float* dw0   = (const float*)d_in[7];
    const float* db0   = (const float*)d_in[8];
    const float* dw1   = (const float*)d_in[9];
    const float* db1   = (const float*)d_in[10];
    float* out = (float*)d_out;
    float* dk  = (float*)d_ws;   // 27 floats

    compute_dk_kernel<<<1, 128, 0, stream>>>(dn, dw0, db0, dw1, db1, dk);

    dim3 grid((OW + 7) / 8, (OH + 7) / 8, (OD + 3) / 4);   // 16 x 16 x 7
    jbf_main_kernel<<<grid, 256, 0, stream>>>(x, guide, rw0, rb0, rw1, rb1, dk, out);
}